// Round 1
// baseline (32387.222 us; speedup 1.0000x reference)
//
#include <hip/hip_runtime.h>

// ---------------- problem constants ----------------
#define BB   64      // batch
#define TT   512     // time steps
#define NVOC 16      // vocab
#define KIN  256     // UNITS (embedding dim)
#define HH   512     // hidden
#define GG   2048    // 4*H gate width
#define FF   64      // final dense features

// ---------------- launch geometry ----------------
#define NWG  256     // workgroups (== #CUs, cooperative)
#define NTHR 512     // threads per WG (8 waves)
#define WGPG 64      // WGs per batch-group
#define NGRP 4       // batch groups (16 batch rows each)
#define BPG  16      // batch rows per group

// ws float layout (after 64-byte counter header):
//   tab1[16*2048] | h1 ping/pong [2][64*512] | h2 ping/pong [2][64*512]
#define TAB1_OFF 0
#define H1_OFF   32768
#define H2_OFF   98304

// Monotonic-target barrier; counter never reset (no reset race).
// RELEASE on the RMW publishes prior h-writes device-wide; ACQUIRE spin
// (buffer_inv) makes remote-XCD writes visible. 1 WG/CU -> spin is harmless.
__device__ __forceinline__ void wg_barrier(unsigned* ctr, unsigned target) {
  __syncthreads();
  if (threadIdx.x == 0) {
    __hip_atomic_fetch_add(ctr, 1u, __ATOMIC_RELEASE, __HIP_MEMORY_SCOPE_AGENT);
    while (__hip_atomic_load(ctr, __ATOMIC_ACQUIRE, __HIP_MEMORY_SCOPE_AGENT) < target) {
      __builtin_amdgcn_s_sleep(2);
    }
  }
  __syncthreads();
}

extern "C" __global__ void __launch_bounds__(NTHR, 2)
lstm_fused(const int* __restrict__ tokens, const float* __restrict__ emb,
           const float* __restrict__ W1, const float* __restrict__ U1,
           const float* __restrict__ b1, const float* __restrict__ W2,
           const float* __restrict__ U2, const float* __restrict__ b2,
           const float* __restrict__ Wd, const float* __restrict__ bd,
           float* __restrict__ out, float* __restrict__ wsf,
           unsigned* __restrict__ ctr)
{
  const int wg   = blockIdx.x;     // 0..255
  const int grp  = wg >> 6;        // batch group 0..3
  const int cb   = wg & 63;        // column block within group
  const int tid  = threadIdx.x;    // 0..511
  const int kq   = tid >> 7;       // K-split quarter 0..3
  const int cell = tid & 127;      // cell within WG
  const int bl   = cell >> 3;      // 0..15 batch row in group
  const int jl   = cell & 7;       // 0..7 hidden col in block
  const int b    = grp * BPG + bl;
  const int jh   = cb * 8 + jl;    // absolute hidden col 0..511
  const int colz = jh;             // z-column for gate 0 (gates at +512g)

  float* tab1 = wsf + TAB1_OFF;
  float* h1b0 = wsf + H1_OFF;
  float* h1b1 = wsf + H1_OFF + BB * HH;
  float* h2b0 = wsf + H2_OFF;
  float* h2b1 = wsf + H2_OFF + BB * HH;

  __shared__ float zred[4][128][4];

  // ---- phase 0: input-projection table (vocab=16!) + zero h state ----
  {
    int g0 = wg * NTHR + tid;           // 0..131071
    if (g0 < NVOC * GG) {               // 32768 entries
      int v = g0 >> 11, col = g0 & (GG - 1);
      float acc = b1[col];
      const float* e = emb + v * KIN;
      const float* w = W1 + col;
      #pragma unroll 4
      for (int k = 0; k < KIN; ++k) acc += e[k] * w[(size_t)k * GG];
      tab1[g0] = acc;
      h1b0[g0] = 0.f;   // t=0 reads buffer 0
      h2b0[g0] = 0.f;
    }
  }
  wg_barrier(&ctr[8], NWG);   // one global barrier: tab1 spans all WGs

  unsigned bt = 0;            // group-barrier monotonic target
  float c1 = 0.f, c2 = 0.f;   // cell states live in registers (kq==0 owners)

  for (int t = 0; t < TT; ++t) {
    float* h1r = (t & 1) ? h1b1 : h1b0;
    float* h1w = (t & 1) ? h1b0 : h1b1;
    float* h2r = (t & 1) ? h2b1 : h2b0;
    float* h2w = (t & 1) ? h2b0 : h2b1;

    // ---------- layer 1: z = tab1[tok] + h1r @ U1 (K=512, quarter=128) ----------
    {
      float z0 = 0.f, z1 = 0.f, z2 = 0.f, z3 = 0.f;
      const int k0 = kq * 128;
      const float4* h4 = reinterpret_cast<const float4*>(h1r + b * HH + k0);
      const float* up = U1 + (size_t)k0 * GG + colz;
      #pragma unroll 2
      for (int k4 = 0; k4 < 32; ++k4) {
        float4 hv = h4[k4];
        const float* u0 = up;
        z0 += hv.x*u0[0]; z1 += hv.x*u0[512]; z2 += hv.x*u0[1024]; z3 += hv.x*u0[1536]; u0 += GG;
        z0 += hv.y*u0[0]; z1 += hv.y*u0[512]; z2 += hv.y*u0[1024]; z3 += hv.y*u0[1536]; u0 += GG;
        z0 += hv.z*u0[0]; z1 += hv.z*u0[512]; z2 += hv.z*u0[1024]; z3 += hv.z*u0[1536]; u0 += GG;
        z0 += hv.w*u0[0]; z1 += hv.w*u0[512]; z2 += hv.w*u0[1024]; z3 += hv.w*u0[1536];
        up += 4 * GG;
      }
      zred[kq][cell][0] = z0; zred[kq][cell][1] = z1;
      zred[kq][cell][2] = z2; zred[kq][cell][3] = z3;
    }
    __syncthreads();
    if (kq == 0) {
      float z0 = zred[0][cell][0]+zred[1][cell][0]+zred[2][cell][0]+zred[3][cell][0];
      float z1 = zred[0][cell][1]+zred[1][cell][1]+zred[2][cell][1]+zred[3][cell][1];
      float z2 = zred[0][cell][2]+zred[1][cell][2]+zred[2][cell][2]+zred[3][cell][2];
      float z3 = zred[0][cell][3]+zred[1][cell][3]+zred[2][cell][3]+zred[3][cell][3];
      int tok = tokens[b * TT + t];
      const float* tb = tab1 + (size_t)tok * GG + colz;
      z0 += tb[0]; z1 += tb[512]; z2 += tb[1024]; z3 += tb[1536];
      float sig_i = 1.f / (1.f + expf(-z0));
      float sig_f = 1.f / (1.f + expf(-z1));
      float g_t   = tanhf(z2);
      float sig_o = 1.f / (1.f + expf(-z3));
      float cn = sig_f * c1 + sig_i * g_t;
      float hn = sig_o * tanhf(cn);
      if (tok == 0) { cn = c1; hn = h1r[b * HH + jh]; }  // mask: keep state
      c1 = cn;
      h1w[b * HH + jh] = hn;
    }
    bt += WGPG;
    wg_barrier(&ctr[grp], bt);

    // ---------- layer 2: z = b2 + h1w @ W2 + h2r @ U2 (K=1024, quarter=256) ----------
    {
      float z0 = 0.f, z1 = 0.f, z2 = 0.f, z3 = 0.f;
      const float* xin = (kq < 2) ? (h1w + b * HH) : (h2r + b * HH);
      const float* WW  = (kq < 2) ? W2 : U2;
      const int k0 = (kq & 1) * 256;
      const float4* h4 = reinterpret_cast<const float4*>(xin + k0);
      const float* up = WW + (size_t)k0 * GG + colz;
      #pragma unroll 2
      for (int k4 = 0; k4 < 64; ++k4) {
        float4 hv = h4[k4];
        const float* u0 = up;
        z0 += hv.x*u0[0]; z1 += hv.x*u0[512]; z2 += hv.x*u0[1024]; z3 += hv.x*u0[1536]; u0 += GG;
        z0 += hv.y*u0[0]; z1 += hv.y*u0[512]; z2 += hv.y*u0[1024]; z3 += hv.y*u0[1536]; u0 += GG;
        z0 += hv.z*u0[0]; z1 += hv.z*u0[512]; z2 += hv.z*u0[1024]; z3 += hv.z*u0[1536]; u0 += GG;
        z0 += hv.w*u0[0]; z1 += hv.w*u0[512]; z2 += hv.w*u0[1024]; z3 += hv.w*u0[1536];
        up += 4 * GG;
      }
      zred[kq][cell][0] = z0; zred[kq][cell][1] = z1;
      zred[kq][cell][2] = z2; zred[kq][cell][3] = z3;
    }
    __syncthreads();
    if (kq == 0) {
      float z0 = zred[0][cell][0]+zred[1][cell][0]+zred[2][cell][0]+zred[3][cell][0];
      float z1 = zred[0][cell][1]+zred[1][cell][1]+zred[2][cell][1]+zred[3][cell][1];
      float z2 = zred[0][cell][2]+zred[1][cell][2]+zred[2][cell][2]+zred[3][cell][2];
      float z3 = zred[0][cell][3]+zred[1][cell][3]+zred[2][cell][3]+zred[3][cell][3];
      int tok = tokens[b * TT + t];
      z0 += b2[colz]; z1 += b2[colz + 512]; z2 += b2[colz + 1024]; z3 += b2[colz + 1536];
      float sig_i = 1.f / (1.f + expf(-z0));
      float sig_f = 1.f / (1.f + expf(-z1));
      float g_t   = tanhf(z2);
      float sig_o = 1.f / (1.f + expf(-z3));
      float cn = sig_f * c2 + sig_i * g_t;
      float hn = sig_o * tanhf(cn);
      if (tok == 0) { cn = c2; hn = h2r[b * HH + jh]; }
      c2 = cn;
      h2w[b * HH + jh] = hn;
    }
    bt += WGPG;
    wg_barrier(&ctr[grp], bt);
  }

  // ---------- final dense: out = h2_final @ Wd + bd ----------
  // t=511 (odd) wrote h2 into buffer 0; group barrier above guarantees our rows.
  if (cb < 4 && tid < 256) {
    int bo = grp * BPG + (cb << 2) + (tid >> 6);  // batch row
    int f  = tid & 63;
    const float* hf = h2b0 + bo * HH;
    const float* wd = Wd + f;
    float acc = bd[f];
    #pragma unroll 4
    for (int k = 0; k < HH; ++k) acc += hf[k] * wd[(size_t)k * FF];
    out[bo * FF + f] = acc;
  }
}

extern "C" void kernel_launch(void* const* d_in, const int* in_sizes, int n_in,
                              void* d_out, int out_size, void* d_ws, size_t ws_size,
                              hipStream_t stream) {
  const int*   tokens = (const int*)  d_in[0];
  const float* emb    = (const float*)d_in[1];
  const float* W1     = (const float*)d_in[2];
  const float* U1     = (const float*)d_in[3];
  const float* b1     = (const float*)d_in[4];
  const float* W2     = (const float*)d_in[5];
  const float* U2     = (const float*)d_in[6];
  const float* b2     = (const float*)d_in[7];
  const float* Wd     = (const float*)d_in[8];
  const float* bd     = (const float*)d_in[9];
  float*    out = (float*)d_out;
  unsigned* ctr = (unsigned*)d_ws;                   // 64-byte counter header
  float*    wsf = (float*)((char*)d_ws + 64);        // ~640 KB float region

  // ws is re-poisoned 0xAA before every timed launch: zero the barrier counters.
  hipMemsetAsync(d_ws, 0, 64, stream);

  void* args[] = { &tokens, &emb, &W1, &U1, &b1, &W2, &U2, &b2, &Wd, &bd,
                   &out, &wsf, &ctr };
  hipLaunchCooperativeKernel((void*)lstm_fused, dim3(NWG), dim3(NTHR),
                             args, 0, stream);
}

// Round 3
// 28018.973 us; speedup vs baseline: 1.1559x; 1.1559x over previous
//
#include <hip/hip_runtime.h>

// ---------------- problem constants ----------------
#define BB   64
#define TT   512
#define NVOC 16
#define KIN  256
#define HH   512
#define GG   2048
#define FF   64

#define NWG  256
#define NTHR 512

// LDS layout (float offsets). Weight rows padded to 524 floats (2096 B:
// lane stride mod 128 = 48 -> 16 zc rows spread over all 8 bank slots, 2-way).
#define U1W_OFF  0
#define W2W_OFF  8384        // 16*524
#define U2W_OFF  16768
#define HLDS_OFF 25152       // [32][256] float, XOR-swizzled at float4 granularity
#define ZRED_OFF 33344       // [8][32][17]
#define TABW_OFF 37696       // [16][16]
#define B2W_OFF  37952       // [16]
#define LDS_FLOATS 37968
#define LDS_BYTES  (LDS_FLOATS * 4)

// ws float layout after 64-byte counter header: h1 ping/pong, h2 ping/pong
#define H1A_OFF 0
#define H1B_OFF 32768
#define H2A_OFF 65536
#define H2B_OFF 98304

// Monotonic-target barrier (proved correct cross-XCD in R1).
__device__ __forceinline__ void wg_barrier(unsigned* ctr, unsigned target) {
  __syncthreads();
  if (threadIdx.x == 0) {
    __hip_atomic_fetch_add(ctr, 1u, __ATOMIC_RELEASE, __HIP_MEMORY_SCOPE_AGENT);
    while (__hip_atomic_load(ctr, __ATOMIC_ACQUIRE, __HIP_MEMORY_SCOPE_AGENT) < target) {
      __builtin_amdgcn_s_sleep(2);
    }
  }
  __syncthreads();
}

// ---- h-chunk staging: global [32][512] slice -> LDS [32][256] swizzled ----
__device__ __forceinline__ void stage_ld(float4 v[4], const float* __restrict__ src, int tid) {
  #pragma unroll
  for (int jj = 0; jj < 4; ++jj) {
    int f4 = jj * 512 + tid;
    int b = f4 >> 6, k4l = f4 & 63;
    v[jj] = *reinterpret_cast<const float4*>(src + b * HH + k4l * 4);
  }
}
__device__ __forceinline__ void stage_st(float* __restrict__ hlds, const float4 v[4], int tid) {
  float4* h4 = reinterpret_cast<float4*>(hlds);
  #pragma unroll
  for (int jj = 0; jj < 4; ++jj) {
    int f4 = jj * 512 + tid;
    int b = f4 >> 6, k4l = f4 & 63;
    h4[b * 64 + (k4l ^ (b >> 3))] = v[jj];   // slot-XOR by row-group: reads conflict-free
  }
}

// ---- inner: 8 j-iters, each 1 w4 + 8 h4 ds_read_b128 + 32 FMA ----
__device__ __forceinline__ void inner8(float acc[8], const float* __restrict__ wrow,
                                       const float4* __restrict__ h4base, int kq8, int bg) {
  #pragma unroll
  for (int j = 0; j < 8; ++j) {
    int k4 = kq8 + j;
    float4 w = *reinterpret_cast<const float4*>(wrow + k4 * 4);
    const float4* hb = h4base + (k4 ^ bg);     // bg-XOR spreads bank slots
    float4 h0 = hb[0 * 64], h1 = hb[1 * 64], h2 = hb[2 * 64], h3 = hb[3 * 64];
    float4 h4v = hb[4 * 64], h5 = hb[5 * 64], h6 = hb[6 * 64], h7 = hb[7 * 64];
    acc[0] += h0.x * w.x; acc[0] += h0.y * w.y; acc[0] += h0.z * w.z; acc[0] += h0.w * w.w;
    acc[1] += h1.x * w.x; acc[1] += h1.y * w.y; acc[1] += h1.z * w.z; acc[1] += h1.w * w.w;
    acc[2] += h2.x * w.x; acc[2] += h2.y * w.y; acc[2] += h2.z * w.z; acc[2] += h2.w * w.w;
    acc[3] += h3.x * w.x; acc[3] += h3.y * w.y; acc[3] += h3.z * w.z; acc[3] += h3.w * w.w;
    acc[4] += h4v.x * w.x; acc[4] += h4v.y * w.y; acc[4] += h4v.z * w.z; acc[4] += h4v.w * w.w;
    acc[5] += h5.x * w.x; acc[5] += h5.y * w.y; acc[5] += h5.z * w.z; acc[5] += h5.w * w.w;
    acc[6] += h6.x * w.x; acc[6] += h6.y * w.y; acc[6] += h6.z * w.z; acc[6] += h6.w * w.w;
    acc[7] += h7.x * w.x; acc[7] += h7.y * w.y; acc[7] += h7.z * w.z; acc[7] += h7.w * w.w;
  }
}

extern "C" __global__ void __launch_bounds__(NTHR, 2)
lstm_fused2(const int* __restrict__ tokens, const float* __restrict__ emb,
            const float* __restrict__ W1, const float* __restrict__ U1,
            const float* __restrict__ b1, const float* __restrict__ W2,
            const float* __restrict__ U2, const float* __restrict__ b2,
            const float* __restrict__ Wd, const float* __restrict__ bd,
            float* __restrict__ out, float* __restrict__ wsf,
            unsigned* __restrict__ ctr)
{
  extern __shared__ float lds[];
  float* u1w  = lds + U1W_OFF;
  float* w2w  = lds + W2W_OFF;
  float* u2w  = lds + U2W_OFF;
  float* hlds = lds + HLDS_OFF;
  float* zred = lds + ZRED_OFF;
  float* tabw = lds + TABW_OFF;
  float* b2w  = lds + B2W_OFF;

  const int wg  = blockIdx.x;
  const int tid = threadIdx.x;
  const int bh  = wg >> 7;        // batch half (0/1): rows bh*32..+31
  const int ct  = wg & 127;       // col tile: hidden cols ct*4..+3
  const int hc0 = ct * 4;
  const int zcl = tid & 15;       // zc index: gate g=zcl>>2, col c=zcl&3
  const int bg  = (tid >> 4) & 3; // 8-row batch group
  const int kq  = tid >> 6;       // wave id = K-split (8-way)
  const int kq8 = kq * 8;

  float* h1A = wsf + H1A_OFF; float* h1B = wsf + H1B_OFF;
  float* h2A = wsf + H2A_OFF; float* h2B = wsf + H2B_OFF;

  // ---------------- phase 0 ----------------
  { // weight slices -> LDS, transposed to [zc][k] rows of 524
    int k = tid;
    #pragma unroll
    for (int g = 0; g < 4; ++g) {
      float4 a = *reinterpret_cast<const float4*>(U1 + (size_t)k * GG + hc0 + 512 * g);
      u1w[(g * 4 + 0) * 524 + k] = a.x; u1w[(g * 4 + 1) * 524 + k] = a.y;
      u1w[(g * 4 + 2) * 524 + k] = a.z; u1w[(g * 4 + 3) * 524 + k] = a.w;
      float4 b_ = *reinterpret_cast<const float4*>(W2 + (size_t)k * GG + hc0 + 512 * g);
      w2w[(g * 4 + 0) * 524 + k] = b_.x; w2w[(g * 4 + 1) * 524 + k] = b_.y;
      w2w[(g * 4 + 2) * 524 + k] = b_.z; w2w[(g * 4 + 3) * 524 + k] = b_.w;
      float4 c_ = *reinterpret_cast<const float4*>(U2 + (size_t)k * GG + hc0 + 512 * g);
      u2w[(g * 4 + 0) * 524 + k] = c_.x; u2w[(g * 4 + 1) * 524 + k] = c_.y;
      u2w[(g * 4 + 2) * 524 + k] = c_.z; u2w[(g * 4 + 3) * 524 + k] = c_.w;
    }
  }
  if (tid < 256) { // token->z1 table restricted to this WG's 16 z-cols (vocab=16)
    int v = tid >> 4, zz = tid & 15;
    int col = hc0 + (zz & 3) + ((zz >> 2) << 9);
    float a = b1[col];
    #pragma unroll 4
    for (int k = 0; k < KIN; ++k) a += emb[v * KIN + k] * W1[(size_t)k * GG + col];
    tabw[v * 16 + zz] = a;
  }
  if (tid < 16) b2w[tid] = b2[hc0 + (tid & 3) + ((tid >> 2) << 9)];
  { // zero t=0 read buffers (own half's slice)
    if (tid < 128)       h1A[bh * 16384 + ct * 128 + tid] = 0.f;
    else if (tid < 256)  h2A[bh * 16384 + ct * 128 + (tid - 128)] = 0.f;
  }
  unsigned bt = 128;
  wg_barrier(&ctr[bh], bt);

  // persistent per-thread state (tid<128 owners): thread = (b = tid>>2, c = tid&3)
  float c1 = 0.f, hp1 = 0.f, c2 = 0.f, hp2 = 0.f;
  const int fb = tid >> 2;          // finalize batch row (local)
  const int fc = tid & 3;           // finalize hidden col (local)

  const float4* h4base = reinterpret_cast<const float4*>(hlds) + bg * 512;
  const float* u1row = u1w + zcl * 524;
  const float* w2row = w2w + zcl * 524;
  const float* u2row = u2w + zcl * 524;

  for (int t = 0; t < TT; ++t) {
    float* h1r = (t & 1) ? h1B : h1A;
    float* h1w = (t & 1) ? h1A : h1B;
    float* h2r = (t & 1) ? h2B : h2A;
    float* h2w = (t & 1) ? h2A : h2B;
    const float* h1r_half = h1r + bh * 32 * HH;
    const float* h2r_half = h2r + bh * 32 * HH;
    const float* h1w_half = h1w + bh * 32 * HH;

    float acc[8] = {0,0,0,0,0,0,0,0};
    float4 pre[4];

    // ---------- layer 1: z1 = tab1[tok] + h1r @ U1 ----------
    stage_ld(pre, h1r_half, tid);                 // chunk 0 (exposed)
    __syncthreads(); stage_st(hlds, pre, tid); __syncthreads();
    stage_ld(pre, h1r_half + 256, tid);           // chunk 1 issued under inner
    inner8(acc, u1row, h4base, kq8, bg);
    __syncthreads(); stage_st(hlds, pre, tid); __syncthreads();
    stage_ld(pre, h2r_half, tid);                 // prefetch U2 chunk 0 (h2r ready)
    inner8(acc, u1row + 256, h4base, kq8, bg);

    __syncthreads();
    #pragma unroll
    for (int i = 0; i < 8; ++i) zred[kq * 544 + (bg * 8 + i) * 17 + zcl] = acc[i];
    __syncthreads();
    if (tid < 128) {
      float z[4];
      #pragma unroll
      for (int g = 0; g < 4; ++g) {
        float s = 0.f;
        #pragma unroll
        for (int q = 0; q < 8; ++q) s += zred[q * 544 + fb * 17 + g * 4 + fc];
        z[g] = s;
      }
      int tok = tokens[(bh * 32 + fb) * TT + t];
      #pragma unroll
      for (int g = 0; g < 4; ++g) z[g] += tabw[tok * 16 + g * 4 + fc];
      float si = 1.f / (1.f + expf(-z[0]));
      float sf = 1.f / (1.f + expf(-z[1]));
      float gg = tanhf(z[2]);
      float so = 1.f / (1.f + expf(-z[3]));
      float cn = sf * c1 + si * gg;
      float hn = so * tanhf(cn);
      if (tok == 0) { cn = c1; hn = hp1; }
      c1 = cn; hp1 = hn;
      h1w[(bh * 32 + fb) * HH + hc0 + fc] = hn;
    }
    bt += 128; wg_barrier(&ctr[bh], bt);

    // ---------- layer 2: z2 = b2 + h1w @ W2 + h2r @ U2 (U2 part first) ----------
    #pragma unroll
    for (int i = 0; i < 8; ++i) acc[i] = 0.f;
    __syncthreads(); stage_st(hlds, pre, tid); __syncthreads();   // U2 chunk 0
    stage_ld(pre, h2r_half + 256, tid);
    inner8(acc, u2row, h4base, kq8, bg);
    __syncthreads(); stage_st(hlds, pre, tid); __syncthreads();   // U2 chunk 1
    stage_ld(pre, h1w_half, tid);                                  // W2 chunk 0 (post-barrier: ready)
    inner8(acc, u2row + 256, h4base, kq8, bg);
    __syncthreads(); stage_st(hlds, pre, tid); __syncthreads();   // W2 chunk 0
    stage_ld(pre, h1w_half + 256, tid);
    inner8(acc, w2row, h4base, kq8, bg);
    __syncthreads(); stage_st(hlds, pre, tid); __syncthreads();   // W2 chunk 1
    inner8(acc, w2row + 256, h4base, kq8, bg);

    __syncthreads();
    #pragma unroll
    for (int i = 0; i < 8; ++i) zred[kq * 544 + (bg * 8 + i) * 17 + zcl] = acc[i];
    __syncthreads();
    if (tid < 128) {
      float z[4];
      #pragma unroll
      for (int g = 0; g < 4; ++g) {
        float s = 0.f;
        #pragma unroll
        for (int q = 0; q < 8; ++q) s += zred[q * 544 + fb * 17 + g * 4 + fc];
        z[g] = s + b2w[g * 4 + fc];
      }
      int tok = tokens[(bh * 32 + fb) * TT + t];
      float si = 1.f / (1.f + expf(-z[0]));
      float sf = 1.f / (1.f + expf(-z[1]));
      float gg = tanhf(z[2]);
      float so = 1.f / (1.f + expf(-z[3]));
      float cn = sf * c2 + si * gg;
      float hn = so * tanhf(cn);
      if (tok == 0) { cn = c2; hn = hp2; }
      c2 = cn; hp2 = hn;
      h2w[(bh * 32 + fb) * HH + hc0 + fc] = hn;
    }
    bt += 128; wg_barrier(&ctr[bh], bt);
  }

  // ---------- final dense: out = h2(t=511, in h2A) @ Wd + bd ----------
  if (ct < 4) {
    int idx = ct * 512 + tid;               // 0..2047 per half
    int b = idx >> 6, f = idx & 63;
    const float* hf = h2A + (bh * 32 + b) * HH;
    float a = bd[f];
    #pragma unroll 8
    for (int k = 0; k < HH; ++k) a += hf[k] * Wd[(size_t)k * FF + f];
    out[(bh * 32 + b) * FF + f] = a;
  }
}

extern "C" void kernel_launch(void* const* d_in, const int* in_sizes, int n_in,
                              void* d_out, int out_size, void* d_ws, size_t ws_size,
                              hipStream_t stream) {
  const int*   tokens = (const int*)  d_in[0];
  const float* emb    = (const float*)d_in[1];
  const float* W1     = (const float*)d_in[2];
  const float* U1     = (const float*)d_in[3];
  const float* b1     = (const float*)d_in[4];
  const float* W2     = (const float*)d_in[5];
  const float* U2     = (const float*)d_in[6];
  const float* b2     = (const float*)d_in[7];
  const float* Wd     = (const float*)d_in[8];
  const float* bd     = (const float*)d_in[9];
  float*    out = (float*)d_out;
  unsigned* ctr = (unsigned*)d_ws;
  float*    wsf = (float*)((char*)d_ws + 64);

  // Host-side module attribute (not a stream op — graph-capture safe);
  // required for >64 KB dynamic LDS.
  hipFuncSetAttribute((const void*)lstm_fused2,
                      hipFuncAttributeMaxDynamicSharedMemorySize, LDS_BYTES);

  hipMemsetAsync(d_ws, 0, 64, stream);   // zero barrier counters

  void* args[] = { &tokens, &emb, &W1, &U1, &b1, &W2, &U2, &b2, &Wd, &bd,
                   &out, &wsf, &ctr };
  hipLaunchCooperativeKernel((void*)lstm_fused2, dim3(NWG), dim3(NTHR),
                             args, LDS_BYTES, stream);
}